// Round 1
// baseline (35.575 us; speedup 1.0000x reference)
//
#include <hip/hip_runtime.h>

#define NBATCH 32
#define NANCH  5
#define NCLS   20
#define NHW    5776          // 76*76
#define NCH    25            // 5 + NCLS
#define NWID   76
#define OUTW   29            // 4 pred_box + 5 fields + 20 cls
#define CELLS  (NBATCH * NANCH * NHW)   // 924160

__global__ __launch_bounds__(256) void region_fwd(
    const float* __restrict__ in,       // (32, 125, 76, 76)
    const float* __restrict__ anchors,  // (5, 2)
    float* __restrict__ out)            // (924160, 29)
{
    // 4 waves per block, each wave stages its 64 rows x 29 cols in LDS
    __shared__ float lds[4][64 * OUTW];   // 29696 B

    const int g    = blockIdx.x * 256 + threadIdx.x;   // cell index, grid exact
    const int wave = threadIdx.x >> 6;
    const int lane = threadIdx.x & 63;

    const int spatial = g % NHW;          // i*76 + j
    const int ba      = g / NHW;          // b*5 + a
    const int a       = ba % NANCH;
    const int j       = spatial % NWID;
    const int i       = spatial / NWID;

    const int in_base = ba * (NCH * NHW) + spatial;

    float v[NCH];
    #pragma unroll
    for (int ch = 0; ch < NCH; ++ch)
        v[ch] = in[in_base + ch * NHW];   // coalesced: lanes -> consecutive spatial

    const float aw = anchors[a * 2 + 0];
    const float ah = anchors[a * 2 + 1];

    const float x    = 1.f / (1.f + __expf(-v[0]));
    const float y    = 1.f / (1.f + __expf(-v[1]));
    const float conf = 1.f / (1.f + __expf(-v[4]));
    const float bw   = __expf(v[2]) * aw;
    const float bh   = __expf(v[3]) * ah;

    float* row = &lds[wave][lane * OUTW];  // stride 29 (odd) -> bank-conflict-free
    row[0] = x + (float)j;
    row[1] = y + (float)i;
    row[2] = bw;
    row[3] = bh;
    row[4] = x;
    row[5] = y;
    row[6] = v[2];
    row[7] = v[3];
    row[8] = conf;
    #pragma unroll
    for (int c = 0; c < NCLS; ++c)
        row[9 + c] = v[5 + c];

    __syncthreads();   // cheap; guarantees LDS visibility before readback

    // coalesced writeback: wave's 1856 contiguous floats, 29 passes of 64 lanes
    const int outBase = (blockIdx.x * 256 + wave * 64) * OUTW;
    #pragma unroll
    for (int k = 0; k < OUTW; ++k)
        out[outBase + k * 64 + lane] = lds[wave][k * 64 + lane];
}

extern "C" void kernel_launch(void* const* d_in, const int* in_sizes, int n_in,
                              void* d_out, int out_size, void* d_ws, size_t ws_size,
                              hipStream_t stream) {
    const float* in      = (const float*)d_in[0];
    const float* anchors = (const float*)d_in[1];
    // d_in[2] (target) unused by the forward transform
    float* out = (float*)d_out;

    region_fwd<<<CELLS / 256, 256, 0, stream>>>(in, anchors, out);
}